// Round 3
// baseline (2086.818 us; speedup 1.0000x reference)
//
#include <hip/hip_runtime.h>
#include <hip/hip_bf16.h>
#include <stdint.h>

#define LB 6
#define BB 32
#define SS 512
#define DD 512
#define HH 8
#define FF_ 2048
#define MM (BB*SS)   // 16384

typedef unsigned short u16;
typedef __attribute__((ext_vector_type(8))) short bf16x8;
typedef __attribute__((ext_vector_type(4))) float f32x4;

#define MFMA16(a,b,c) __builtin_amdgcn_mfma_f32_16x16x32_bf16((a),(b),(c),0,0,0)
#define GLD16(g, l) __builtin_amdgcn_global_load_lds( \
    (const __attribute__((address_space(1))) unsigned int*)(g), \
    (__attribute__((address_space(3))) unsigned int*)(l), 16, 0, 0)

__device__ __forceinline__ u16 f2b(float f){
  unsigned int u = __float_as_uint(f);
  u = u + 0x7FFFu + ((u >> 16) & 1u);
  return (u16)(u >> 16);
}

// gelu via sigmoid identity: 0.5x(1+tanh(u)) == x * sigmoid(2u)
__device__ __forceinline__ float gelu_f(float x){
  float u2 = 1.5957691216057308f * (x + 0.044715f * x * x * x);  // 2*sqrt(2/pi)*(...)
  return x / (1.0f + __expf(-u2));
}

// ---------------- prep: h(fp32)=x, hbf=bf16(x) ----------------
__global__ __launch_bounds__(256) void k_prep(const float* __restrict__ x,
                                              float* __restrict__ h,
                                              u16* __restrict__ hb){
  int i = blockIdx.x * 256 + threadIdx.x;
  float4 v = ((const float4*)x)[i];
  ((float4*)h)[i] = v;
  uint2 p;
  p.x = (unsigned)f2b(v.x) | ((unsigned)f2b(v.y) << 16);
  p.y = (unsigned)f2b(v.z) | ((unsigned)f2b(v.w) << 16);
  ((uint2*)hb)[i] = p;
}

// ---------------- weight transpose + bf16 cast: out[n][k] = in[k][n] ----------------
__global__ __launch_bounds__(256) void k_wt(const float* __restrict__ in,
                                            u16* __restrict__ out, int K, int N){
  size_t ms = (size_t)K * N;
  in  += ms * blockIdx.z;
  out += ms * blockIdx.z;
  int n0 = blockIdx.x * 64, k0 = blockIdx.y * 64;
  __shared__ float tile[64][65];
  int t = threadIdx.x;
  int c = t & 63, rb = t >> 6;
  #pragma unroll
  for (int p = 0; p < 16; p++){
    int k = p * 4 + rb;
    tile[k][c] = in[(size_t)(k0 + k) * N + (n0 + c)];
  }
  __syncthreads();
  #pragma unroll
  for (int p = 0; p < 16; p++){
    int n = p * 4 + rb;
    out[(size_t)(n0 + n) * K + (k0 + c)] = f2b(tile[c][n]);
  }
}

// ---------------- GEMM: out[m][n] = sum_k A[m][k]*Bt[n][k], 128x128 tile ----------------
// LDS layout (per 128x32 tile, 16B units): [frag i:0..7][kchunk:0..3][row16:0..15]
//   slot s (0..511) holds global (row = (s>>6)*16 + (s&15), k = ((s>>4)&3)*8 .. +7)
//   => stage write  : lds addr16 = s          (linear, matches global_load_lds)
//   => frag read    : lds addr16 = i*64+lane  (base + lane*16B, conflict-free)
// EPI: 0 = bf16 store, 1 = fp32 store, 2 = bias+gelu -> bf16, 3 = bias -> fp32
template<int EPI, bool PERM>
__device__ __forceinline__ void gemm_body(const u16* __restrict__ A, const u16* __restrict__ Bt,
    const float* __restrict__ bias, float* __restrict__ outF, u16* __restrict__ outH,
    int N, int K)
{
  __shared__ u16 sA0[4096], sB0[4096], sA1[4096], sB1[4096];  // 2 x 8KB x 2 bufs
  const int t = threadIdx.x;
  const int w = t >> 6, lane = t & 63, lr = lane & 15, lh = lane >> 4;
  const int bm = blockIdx.x * 128, bn = blockIdx.y * 128;
  const int wr = (w >> 1) * 64, wc = (w & 1) * 64;

  f32x4 acc[4][4];
  #pragma unroll
  for (int i = 0; i < 4; i++)
    #pragma unroll
    for (int j = 0; j < 4; j++) acc[i][j] = (f32x4){0.f,0.f,0.f,0.f};

  // staging source addresses: thread t covers slot t (i=w) and slot t+256 (i=w+4)
  const int lr_s = t & 15;
  const int kch  = ((t >> 4) & 3) * 8;
  const int arow0 = w * 16 + lr_s;          // rows 0..63
  int b0 = bn + arow0, b1 = bn + arow0 + 64;
  if (PERM){  // head-interleave fold: output col n <- source col (n&63)*8 + (n>>6)
    b0 = ((b0 & 63) << 3) | (b0 >> 6);
    b1 = ((b1 & 63) << 3) | (b1 >> 6);
  }
  const u16* gA0 = A  + (size_t)(bm + arow0) * K + kch;
  const u16* gA1 = gA0 + (size_t)64 * K;
  const u16* gB0 = Bt + (size_t)b0 * K + kch;
  const u16* gB1 = Bt + (size_t)b1 * K + kch;
  const int wofs = w * 512;   // u16 wave base inside each 4KB half

  auto stage = [&](u16* dA, u16* dB, int k0){
    GLD16(gA0 + k0, dA + wofs);
    GLD16(gA1 + k0, dA + 2048 + wofs);
    GLD16(gB0 + k0, dB + wofs);
    GLD16(gB1 + k0, dB + 2048 + wofs);
  };
  const int iA = (w >> 1) * 4, iB = (w & 1) * 4;
  auto phase = [&](const u16* cA, const u16* cB, u16* nA, u16* nB, int knext, bool dostage){
    bf16x8 af[4], bfr[4];
    #pragma unroll
    for (int i = 0; i < 4; i++) af[i]  = *(const bf16x8*)&cA[(iA + i)*512 + lane*8];
    #pragma unroll
    for (int j = 0; j < 4; j++) bfr[j] = *(const bf16x8*)&cB[(iB + j)*512 + lane*8];
    if (dostage) stage(nA, nB, knext);
    #pragma unroll
    for (int i = 0; i < 4; i++)
      #pragma unroll
      for (int j = 0; j < 4; j++)
        acc[i][j] = MFMA16(af[i], bfr[j], acc[i][j]);
  };

  const int NT = K >> 5;      // K-steps of 32; NT is even (16 or 64)
  stage(sA0, sB0, 0);
  __syncthreads();
  #pragma unroll 1
  for (int kt = 0; kt < NT; kt += 2){
    phase(sA0, sB0, sA1, sB1, (kt+1) << 5, true);
    __syncthreads();
    bool more = (kt + 2 < NT);
    phase(sA1, sB1, sA0, sB0, (kt+2) << 5, more);
    if (more) __syncthreads();
  }

  #pragma unroll
  for (int i = 0; i < 4; i++){
    int row = bm + wr + i*16 + lh*4;
    #pragma unroll
    for (int j = 0; j < 4; j++){
      int col = bn + wc + j*16 + lr;
      float bv = (EPI >= 2) ? bias[col] : 0.f;
      #pragma unroll
      for (int r = 0; r < 4; r++){
        float v = acc[i][j][r];
        size_t o = (size_t)(row + r) * N + col;
        if (EPI == 0) outH[o] = f2b(v);
        else if (EPI == 1) outF[o] = v;
        else if (EPI == 2) outH[o] = f2b(gelu_f(v + bv));
        else outF[o] = v + bv;
      }
    }
  }
}

template<int EPI>
__global__ __launch_bounds__(256) void k_gemm(const u16* A, const u16* Bt, const float* bias,
                                              float* outF, u16* outH, int N, int K){
  gemm_body<EPI,false>(A, Bt, bias, outF, outH, N, K);
}

__global__ __launch_bounds__(256) void k_qkv(const u16* A, const u16* Bq, const u16* Bk, const u16* Bv,
                                             u16* oq, u16* ok, u16* ov){
  const u16* Bt = (blockIdx.z == 0) ? Bq : (blockIdx.z == 1) ? Bk : Bv;
  u16* out = (blockIdx.z == 0) ? oq : (blockIdx.z == 1) ? ok : ov;
  gemm_body<0,true>(A, Bt, nullptr, nullptr, out, DD, DD);
}

// ---------------- flash attention: block = (qtile 64, head, batch), 4 waves ----------------
__global__ __launch_bounds__(256) void k_attn(const u16* __restrict__ Q, const u16* __restrict__ Kp,
                                              const u16* __restrict__ V, u16* __restrict__ O){
  const int qt = blockIdx.x, hh = blockIdx.y, b = blockIdx.z;
  __shared__ u16 Qs[64*64];
  __shared__ u16 Ks[64*64];
  __shared__ u16 Vt[64*64];   // transposed [dk][kv], double-key swizzled
  __shared__ u16 Ps[64*64];   // P tile, per-wave rows, swizzled
  const int t = threadIdx.x, w = t >> 6, lane = t & 63, lr = lane & 15, lh = lane >> 4;
  const size_t base = ((size_t)b * SS) * DD + (size_t)hh * 64;

  const int srow = t >> 3;                               // 0..31 (+32 for 2nd pass)
  const int gcol = (((t & 7) ^ (srow & 7)) << 3);        // pre-swizzled source column
  {
    const u16* g = Q + base + (size_t)(qt*64 + srow) * DD + gcol;
    GLD16(g,                   Qs + w*512);
    GLD16(g + (size_t)32*DD,   Qs + 2048 + w*512);
  }

  float mreg[4], lreg[4];
  f32x4 ofr[4];
  #pragma unroll
  for (int r = 0; r < 4; r++){ mreg[r] = -1e30f; lreg[r] = 0.f; }
  #pragma unroll
  for (int j = 0; j < 4; j++) ofr[j] = (f32x4){0.f,0.f,0.f,0.f};

  const int qswz = (lr & 7) << 3;

  for (int kt = 0; kt < 8; kt++){
    {
      const u16* g = Kp + base + (size_t)(kt*64 + srow) * DD + gcol;
      GLD16(g,                 Ks + w*512);
      GLD16(g + (size_t)32*DD, Ks + 2048 + w*512);
    }
    {
      const int dk0 = (t & 7) * 8, kv = (t >> 3) * 2;
      const u16* g = V + base + (size_t)(kt*64 + kv) * DD + dk0;
      uint4 r0 = *(const uint4*)g;
      uint4 r1 = *(const uint4*)(g + DD);
      const u16* e0 = (const u16*)&r0;
      const u16* e1 = (const u16*)&r1;
      #pragma unroll
      for (int i = 0; i < 8; i++){
        int dk = dk0 + i;
        int sw = ((((dk >> 3) ^ dk) & 7) << 3);
        *(unsigned int*)&Vt[dk*64 + (kv ^ sw)] =
            (unsigned int)e0[i] | ((unsigned int)e1[i] << 16);
      }
    }
    __syncthreads();

    // QK^T (16 rows per wave x 64 kv cols)
    bf16x8 a0 = *(const bf16x8*)&Qs[(w*16+lr)*64 + ((lh*8) ^ qswz)];
    bf16x8 a1 = *(const bf16x8*)&Qs[(w*16+lr)*64 + ((32 + lh*8) ^ qswz)];
    f32x4 sc[4];
    #pragma unroll
    for (int j = 0; j < 4; j++){
      bf16x8 b0 = *(const bf16x8*)&Ks[(j*16+lr)*64 + ((lh*8) ^ qswz)];
      bf16x8 b1 = *(const bf16x8*)&Ks[(j*16+lr)*64 + ((32 + lh*8) ^ qswz)];
      f32x4 z = (f32x4){0.f,0.f,0.f,0.f};
      z = MFMA16(a0, b0, z);
      z = MFMA16(a1, b1, z);
      sc[j] = z;
    }

    // online softmax (rows = lh*4+r, reduce across 16 lanes)
    float pr[4][4];
    float esc[4];
    #pragma unroll
    for (int r = 0; r < 4; r++){
      float mx = fmaxf(fmaxf(sc[0][r], sc[1][r]), fmaxf(sc[2][r], sc[3][r]));
      mx = fmaxf(mx, __shfl_xor(mx, 1));
      mx = fmaxf(mx, __shfl_xor(mx, 2));
      mx = fmaxf(mx, __shfl_xor(mx, 4));
      mx = fmaxf(mx, __shfl_xor(mx, 8));
      mx *= 0.125f;   // scale by 1/sqrt(64) (monotone, safe to scale max)
      float m2 = fmaxf(mreg[r], mx);
      float scl = __expf(mreg[r] - m2);
      mreg[r] = m2;
      float s = 0.f;
      #pragma unroll
      for (int j = 0; j < 4; j++){
        float p = __expf(sc[j][r]*0.125f - m2);
        pr[j][r] = p;
        s += p;
      }
      s += __shfl_xor(s, 1);
      s += __shfl_xor(s, 2);
      s += __shfl_xor(s, 4);
      s += __shfl_xor(s, 8);
      lreg[r] = lreg[r]*scl + s;
      esc[r] = scl;
    }

    // write P (bf16, swizzled); each wave owns its 16 rows -> no barrier needed
    #pragma unroll
    for (int j = 0; j < 4; j++)
      #pragma unroll
      for (int r = 0; r < 4; r++){
        int prow = w*16 + lh*4 + r;
        int pcol = j*16 + lr;
        Ps[prow*64 + (pcol ^ (((lh*4 + r) & 7) << 3))] = f2b(pr[j][r]);
      }

    // rescale O
    #pragma unroll
    for (int j = 0; j < 4; j++)
      #pragma unroll
      for (int r = 0; r < 4; r++) ofr[j][r] *= esc[r];

    // PV
    bf16x8 pa0 = *(const bf16x8*)&Ps[(w*16+lr)*64 + ((lh*8) ^ qswz)];
    bf16x8 pa1 = *(const bf16x8*)&Ps[(w*16+lr)*64 + ((32 + lh*8) ^ qswz)];
    #pragma unroll
    for (int j = 0; j < 4; j++){
      int dkr = j*16 + lr;
      int sw = ((((dkr >> 3) ^ dkr) & 7) << 3);
      bf16x8 v0 = *(const bf16x8*)&Vt[dkr*64 + ((lh*8) ^ sw)];
      bf16x8 v1 = *(const bf16x8*)&Vt[dkr*64 + ((32 + lh*8) ^ sw)];
      ofr[j] = MFMA16(pa0, v0, ofr[j]);
      ofr[j] = MFMA16(pa1, v1, ofr[j]);
    }
    __syncthreads();
  }

  #pragma unroll
  for (int j = 0; j < 4; j++)
    #pragma unroll
    for (int r = 0; r < 4; r++){
      float v = ofr[j][r] / lreg[r];
      O[base + (size_t)(qt*64 + w*16 + lh*4 + r) * DD + j*16 + lr] = f2b(v);
    }
}

// ---------------- fused residual add + LayerNorm: h = LN(hin + add) ----------------
__global__ __launch_bounds__(256) void k_ln(const float* __restrict__ hin, const float* __restrict__ add,
    const float* __restrict__ g, const float* __restrict__ be,
    float* __restrict__ hout, u16* __restrict__ hb){
  const int row = blockIdx.x;
  const int t = threadIdx.x;
  const size_t baseo = (size_t)row * DD;
  float v0 = hin[baseo + t]       + add[baseo + t];
  float v1 = hin[baseo + t + 256] + add[baseo + t + 256];
  float s = v0 + v1, q = v0*v0 + v1*v1;
  #pragma unroll
  for (int m = 32; m >= 1; m >>= 1){ s += __shfl_xor(s, m); q += __shfl_xor(q, m); }
  __shared__ float sh[8];
  const int w = t >> 6;
  if ((t & 63) == 0){ sh[w] = s; sh[4 + w] = q; }
  __syncthreads();
  s = sh[0] + sh[1] + sh[2] + sh[3];
  q = sh[4] + sh[5] + sh[6] + sh[7];
  float mean = s * (1.f/512.f);
  float var  = q * (1.f/512.f) - mean*mean;
  float rstd = rsqrtf(var + 1e-5f);
  float o0 = g[t]     * ((v0 - mean) * rstd) + be[t];
  float o1 = g[t+256] * ((v1 - mean) * rstd) + be[t+256];
  hout[baseo + t]       = o0;
  hout[baseo + t + 256] = o1;
  hb[baseo + t]       = f2b(o0);
  hb[baseo + t + 256] = f2b(o1);
}

// ---------------- launch ----------------
extern "C" void kernel_launch(void* const* d_in, const int* in_sizes, int n_in,
                              void* d_out, int out_size, void* d_ws, size_t ws_size,
                              hipStream_t stream){
  const float* x   = (const float*)d_in[0];
  const float* WQ  = (const float*)d_in[1];
  const float* WK  = (const float*)d_in[2];
  const float* WV  = (const float*)d_in[3];
  const float* WO  = (const float*)d_in[4];
  const float* K1  = (const float*)d_in[5];
  const float* B1  = (const float*)d_in[6];
  const float* K2  = (const float*)d_in[7];
  const float* B2  = (const float*)d_in[8];
  const float* G1  = (const float*)d_in[9];
  const float* BE1 = (const float*)d_in[10];
  const float* G2  = (const float*)d_in[11];
  const float* BE2 = (const float*)d_in[12];
  float* hF = (float*)d_out;

  char* wp = (char*)d_ws;
  size_t off = 0;
  auto a16 = [&](size_t elems)->u16*{ u16* p = (u16*)(wp + off); off += elems*sizeof(u16); return p; };
  u16* WQt = a16((size_t)LB*DD*DD);
  u16* WKt = a16((size_t)LB*DD*DD);
  u16* WVt = a16((size_t)LB*DD*DD);
  u16* WOt = a16((size_t)LB*DD*DD);
  u16* K1t = a16((size_t)LB*DD*FF_);
  u16* K2t = a16((size_t)LB*DD*FF_);
  u16* hbf = a16((size_t)MM*DD);
  u16* qbf = a16((size_t)MM*DD);
  u16* kbf = a16((size_t)MM*DD);
  u16* vbf = a16((size_t)MM*DD);
  u16* abf = a16((size_t)MM*DD);
  u16* ff1 = qbf;  // alias: qbf..abf region = MM x FF_ bf16, q/k/v/a dead when ff1 is live
  float* tmpF = (float*)(wp + off); off += (size_t)MM*DD*sizeof(float);
  (void)ws_size; (void)in_sizes; (void)n_in; (void)out_size;

  k_prep<<<MM*DD/4/256, 256, 0, stream>>>(x, hF, hbf);
  k_wt<<<dim3(8,8,LB),        256, 0, stream>>>(WQ, WQt, DD, DD);
  k_wt<<<dim3(8,8,LB),        256, 0, stream>>>(WK, WKt, DD, DD);
  k_wt<<<dim3(8,8,LB),        256, 0, stream>>>(WV, WVt, DD, DD);
  k_wt<<<dim3(8,8,LB),        256, 0, stream>>>(WO, WOt, DD, DD);
  k_wt<<<dim3(FF_/64,8,LB),   256, 0, stream>>>(K1, K1t, DD, FF_);
  k_wt<<<dim3(8,FF_/64,LB),   256, 0, stream>>>(K2, K2t, FF_, DD);

  for (int l = 0; l < LB; l++){
    const u16* wq = WQt + (size_t)l*DD*DD;
    const u16* wk = WKt + (size_t)l*DD*DD;
    const u16* wv = WVt + (size_t)l*DD*DD;
    const u16* wo = WOt + (size_t)l*DD*DD;
    const u16* k1 = K1t + (size_t)l*DD*FF_;
    const u16* k2 = K2t + (size_t)l*DD*FF_;

    k_qkv<<<dim3(MM/128, DD/128, 3), 256, 0, stream>>>(hbf, wq, wk, wv, qbf, kbf, vbf);
    k_attn<<<dim3(SS/64, HH, BB), 256, 0, stream>>>(qbf, kbf, vbf, abf);
    k_gemm<1><<<dim3(MM/128, DD/128), 256, 0, stream>>>(abf, wo, nullptr, tmpF, nullptr, DD, DD);
    k_ln<<<MM, 256, 0, stream>>>(hF, tmpF, G1 + l*DD, BE1 + l*DD, hF, hbf);
    k_gemm<2><<<dim3(MM/128, FF_/128), 256, 0, stream>>>(hbf, k1, B1 + (size_t)l*FF_, nullptr, ff1, FF_, DD);
    k_gemm<3><<<dim3(MM/128, DD/128), 256, 0, stream>>>(ff1, k2, B2 + l*DD, tmpF, nullptr, DD, FF_);
    k_ln<<<MM, 256, 0, stream>>>(hF, tmpF, G2 + l*DD, BE2 + l*DD, hF, hbf);
  }
}

// Round 4
// 1853.624 us; speedup vs baseline: 1.1258x; 1.1258x over previous
//
#include <hip/hip_runtime.h>
#include <hip/hip_bf16.h>
#include <stdint.h>

#define LB 6
#define BB 32
#define SS 512
#define DD 512
#define HH 8
#define FF_ 2048
#define MM (BB*SS)   // 16384

typedef unsigned short u16;
typedef __attribute__((ext_vector_type(8))) short bf16x8;
typedef __attribute__((ext_vector_type(4))) float f32x4;

#define MFMA16(a,b,c) __builtin_amdgcn_mfma_f32_16x16x32_bf16((a),(b),(c),0,0,0)
#define GLD16(g, l) __builtin_amdgcn_global_load_lds( \
    (const __attribute__((address_space(1))) unsigned int*)(g), \
    (__attribute__((address_space(3))) unsigned int*)(l), 16, 0, 0)
#define BAR() asm volatile("s_barrier" ::: "memory")
#define VMW(n) asm volatile("s_waitcnt vmcnt(" #n ")" ::: "memory")

__device__ __forceinline__ u16 f2b(float f){
  unsigned int u = __float_as_uint(f);
  u = u + 0x7FFFu + ((u >> 16) & 1u);
  return (u16)(u >> 16);
}

// gelu via sigmoid identity: 0.5x(1+tanh(u)) == x * sigmoid(2u)
__device__ __forceinline__ float gelu_f(float x){
  float u2 = 1.5957691216057308f * (x + 0.044715f * x * x * x);
  return x / (1.0f + __expf(-u2));
}

// ---------------- prep: h(fp32)=x, hbf=bf16(x) ----------------
__global__ __launch_bounds__(256) void k_prep(const float* __restrict__ x,
                                              float* __restrict__ h,
                                              u16* __restrict__ hb){
  int i = blockIdx.x * 256 + threadIdx.x;
  float4 v = ((const float4*)x)[i];
  ((float4*)h)[i] = v;
  uint2 p;
  p.x = (unsigned)f2b(v.x) | ((unsigned)f2b(v.y) << 16);
  p.y = (unsigned)f2b(v.z) | ((unsigned)f2b(v.w) << 16);
  ((uint2*)hb)[i] = p;
}

// ---------------- weight transpose + bf16 cast: out[n][k] = in[k][n] ----------------
__global__ __launch_bounds__(256) void k_wt(const float* __restrict__ in,
                                            u16* __restrict__ out, int K, int N){
  size_t ms = (size_t)K * N;
  in  += ms * blockIdx.z;
  out += ms * blockIdx.z;
  int n0 = blockIdx.x * 64, k0 = blockIdx.y * 64;
  __shared__ float tile[64][65];
  int t = threadIdx.x;
  int c = t & 63, rb = t >> 6;
  #pragma unroll
  for (int p = 0; p < 16; p++){
    int k = p * 4 + rb;
    tile[k][c] = in[(size_t)(k0 + k) * N + (n0 + c)];
  }
  __syncthreads();
  #pragma unroll
  for (int p = 0; p < 16; p++){
    int n = p * 4 + rb;
    out[(size_t)(n0 + n) * K + (k0 + c)] = f2b(tile[c][n]);
  }
}

// ================ 8-phase 256-wide GEMM (T3+T4+T5, conflict-free frag-major LDS) ================
// out[m][n] = sum_k A[m][k]*Bt[n][k].  BM=256, BK=64, 8 waves (512 thr).
// BN=256: waves 2x4 (per-wave 128x64, acc[8][4]); BN=128: waves 4x2 (per-wave 64x64, acc[4][4]).
// LDS frag-major: half = 16 frags(8 m/n-frags x 2 ksub) x 64 lanes x 16B; stage dest and
// frag read are both base + lane*16B (conflict-free); source address carries the permutation.
// Schedule per iteration (tiles t0=2i -> buf0, t1 -> buf1), 1 half staged per phase:
//  ph1 A0(t1) ph2 A1(t1) ph3 B0(t0+2) ph4 B1(t0+2) [vmcnt] ph5 A0(t0+2) ph6 A1(t0+2)
//  ph7 B0(t0+3) ph8 B1(t0+3) [vmcnt].  B region of a buf is consumed (into regs) in its
//  tile's first phase; A halves only restaged while the other buf is being computed.
// EPI: 0 bf16, 1 fp32, 2 bias+gelu bf16, 3 bias fp32.  PERM: fused QKV head-fold.
template<int BN, int EPI, bool PERM>
__global__ __launch_bounds__(512, 1) void k_gemm8(
    const u16* __restrict__ A,
    const u16* __restrict__ Bq, const u16* __restrict__ Bk, const u16* __restrict__ Bv,
    const float* __restrict__ bias, float* __restrict__ outF, u16* __restrict__ outH,
    int N, int K)
{
  constexpr int WM = (BN==256) ? 2 : 4;
  constexpr int MR = 16/WM;                  // m-frags per wave: 8 or 4
  constexpr int MQ = MR/4;                   // m-frags per phase: 2 or 1
  constexpr int BHALF = (BN==256) ? 8192 : 4096;  // u16 per B half
  constexpr int BBUF  = 2*BHALF;
  constexpr int BL    = (BN==256) ? 2 : 1;   // GLD16 per B-half per thread
  constexpr int HC    = (BN==256) ? 128 : 64;
  __shared__ u16 sM[32768 + 2*BBUF];

  const int t = threadIdx.x;
  const int lane = t & 63, w = t >> 6, lr = lane & 15, lh = lane >> 4;
  const int wm = (BN==256) ? (w>>2) : (w>>1);
  const int wn = (BN==256) ? (w&3)  : (w&1);
  const int bm = blockIdx.x * 256, bn = blockIdx.y * BN;
  const int NTT = K >> 6, NIT = NTT >> 1;
  const int tz = PERM ? (bn >> 9) : 0;

  // ---- staging source addresses (slot p = t, second slot p = t+512) ----
  const int skA = (((t>>6)&1)<<5) + (((t>>4)&3)<<3);  // k offset within 64-wide tile
  const int srA = ((t>>7)<<4) + (t&15);               // row/col within half
  const u16* gA0 = A + (size_t)(bm +       srA) * K + skA;
  const u16* gA1 = A + (size_t)(bm + 128 + srA) * K + skA;
  const u16* gBp[2][2];
  {
    const u16* Bsel = PERM ? (tz==0 ? Bq : tz==1 ? Bk : Bv) : Bq;
    #pragma unroll
    for (int h = 0; h < 2; h++){
      #pragma unroll
      for (int s = 0; s < BL; s++){
        int n = (PERM ? (bn & 511) : bn) + h*HC + srA + s*64;
        int srow = PERM ? (((n & 63) << 3) | (n >> 6)) : n;
        gBp[h][s] = Bsel + (size_t)srow * K + skA;
      }
    }
  }

  auto stageA = [&](int kt, int h){
    u16* dst = sM + (kt&1)*16384 + h*8192 + t*8;
    const u16* src = (h ? gA1 : gA0) + kt*64;
    GLD16(src, dst);
    GLD16(src + (size_t)64*K, dst + 4096);
  };
  auto stageB = [&](int kt, int h){
    u16* dst = sM + 32768 + (kt&1)*BBUF + h*BHALF + t*8;
    GLD16(gBp[h][0] + kt*64, dst);
    if constexpr (BL == 2) GLD16(gBp[h][1] + kt*64, dst + 4096);
  };

  // ---- read bases ----
  const int ha    = (BN==256) ? wm : (wm>>1);
  const int mbase = (BN==256) ? 0  : ((wm&1)*4);
  const int hbi   = (BN==256) ? (wn>>1) : wn;
  const int nfb   = (BN==256) ? ((wn&1)*4) : 0;
  const int rdAbase = ha*8192 + lane*8;
  const int rdBbase = 32768 + hbi*BHALF + nfb*1024 + lane*8;

  f32x4 acc[MR][4];
  #pragma unroll
  for (int i = 0; i < MR; i++)
    #pragma unroll
    for (int j = 0; j < 4; j++) acc[i][j] = (f32x4){0.f,0.f,0.f,0.f};
  bf16x8 bfr[4][2];

#define RD_A(d, q, af) { _Pragma("unroll") for (int i=0;i<MQ;i++){ _Pragma("unroll") for (int ks=0;ks<2;ks++) \
    af[i][ks] = *(const bf16x8*)&sM[(d)*16384 + rdAbase + ((mbase + (q)*MQ + i)*2 + ks)*512]; } }
#define RD_B(d) { _Pragma("unroll") for (int j=0;j<4;j++){ _Pragma("unroll") for (int ks=0;ks<2;ks++) \
    bfr[j][ks] = *(const bf16x8*)&sM[(d)*BBUF + rdBbase + ((j)*2 + (ks))*512]; } }
#define FMA_Q(q, af) { __builtin_amdgcn_s_setprio(1); \
  _Pragma("unroll") for (int i=0;i<MQ;i++){ _Pragma("unroll") for (int j=0;j<4;j++){ _Pragma("unroll") for (int ks=0;ks<2;ks++) \
    acc[(q)*MQ+i][j] = MFMA16(af[i][ks], bfr[j][ks], acc[(q)*MQ+i][j]); } } \
  __builtin_amdgcn_s_setprio(0); }

  // ---- prologue: tile0 fully, B halves of tile1; leave B(1) in flight ----
  stageA(0,0); stageA(0,1); stageB(0,0); stageB(0,1); stageB(1,0); stageB(1,1);
  if constexpr (BL == 2) { VMW(4); } else { VMW(2); }
  BAR();

  for (int it = 0; it < NIT; ++it){
    const int t0 = it*2;
    const bool lastit = (it == NIT-1);
    bf16x8 af[MQ][2];
    // ---- tile t0 (buf0) ----
    RD_A(0,0,af); RD_B(0); stageA(t0+1, 0);            BAR(); FMA_Q(0, af); BAR();
    RD_A(0,1,af);          stageA(t0+1, 1);            BAR(); FMA_Q(1, af); BAR();
    RD_A(0,2,af); if (t0+2 < NTT) stageB(t0+2, 0);     BAR(); FMA_Q(2, af); BAR();
    RD_A(0,3,af); if (t0+2 < NTT) stageB(t0+2, 1);     BAR(); FMA_Q(3, af);
    if (lastit) { VMW(0); } else { if constexpr (BL == 2) { VMW(4); } else { VMW(2); } }
    BAR();
    // ---- tile t0+1 (buf1) ----
    RD_A(1,0,af); RD_B(1); if (t0+2 < NTT) stageA(t0+2, 0); BAR(); FMA_Q(0, af); BAR();
    RD_A(1,1,af);          if (t0+2 < NTT) stageA(t0+2, 1); BAR(); FMA_Q(1, af); BAR();
    RD_A(1,2,af); if (t0+3 < NTT) stageB(t0+3, 0);     BAR(); FMA_Q(2, af); BAR();
    RD_A(1,3,af); if (t0+3 < NTT) stageB(t0+3, 1);     BAR(); FMA_Q(3, af);
    if (!lastit) { if constexpr (BL == 2) { VMW(4); } else { VMW(2); } }
    BAR();
  }
#undef RD_A
#undef RD_B
#undef FMA_Q

  // ---- epilogue ----
  #pragma unroll
  for (int mf = 0; mf < MR; mf++){
    const int row = bm + wm*(256/WM) + mf*16 + lh*4;
    #pragma unroll
    for (int j = 0; j < 4; j++){
      const int col = (PERM ? (bn & 511) : bn) + wn*64 + j*16 + lr;
      float bv = (EPI >= 2) ? bias[col] : 0.f;
      #pragma unroll
      for (int r = 0; r < 4; r++){
        float v = acc[mf][j][r];
        size_t o = (size_t)(row + r) * N + col;
        if (PERM) o += (size_t)tz * ((size_t)MM * DD);
        if (EPI == 0) outH[o] = f2b(v);
        else if (EPI == 1) outF[o] = v;
        else if (EPI == 2) outH[o] = f2b(gelu_f(v + bv));
        else outF[o] = v + bv;
      }
    }
  }
}

// ---------------- flash attention: block = (qtile 64, head, batch), 4 waves ----------------
__global__ __launch_bounds__(256) void k_attn(const u16* __restrict__ Q, const u16* __restrict__ Kp,
                                              const u16* __restrict__ V, u16* __restrict__ O){
  const int qt = blockIdx.x, hh = blockIdx.y, b = blockIdx.z;
  __shared__ u16 Qs[64*64];
  __shared__ u16 Ks[64*64];
  __shared__ u16 Vt[64*64];   // transposed [dk][kv], double-key swizzled
  __shared__ u16 Ps[64*64];   // P tile, per-wave rows, swizzled
  const int t = threadIdx.x, w = t >> 6, lane = t & 63, lr = lane & 15, lh = lane >> 4;
  const size_t base = ((size_t)b * SS) * DD + (size_t)hh * 64;

  const int srow = t >> 3;
  const int gcol = (((t & 7) ^ (srow & 7)) << 3);
  {
    const u16* g = Q + base + (size_t)(qt*64 + srow) * DD + gcol;
    GLD16(g,                   Qs + w*512);
    GLD16(g + (size_t)32*DD,   Qs + 2048 + w*512);
  }

  float mreg[4], lreg[4];
  f32x4 ofr[4];
  #pragma unroll
  for (int r = 0; r < 4; r++){ mreg[r] = -1e30f; lreg[r] = 0.f; }
  #pragma unroll
  for (int j = 0; j < 4; j++) ofr[j] = (f32x4){0.f,0.f,0.f,0.f};

  const int qswz = (lr & 7) << 3;

  for (int kt = 0; kt < 8; kt++){
    {
      const u16* g = Kp + base + (size_t)(kt*64 + srow) * DD + gcol;
      GLD16(g,                 Ks + w*512);
      GLD16(g + (size_t)32*DD, Ks + 2048 + w*512);
    }
    {
      const int dk0 = (t & 7) * 8, kv = (t >> 3) * 2;
      const u16* g = V + base + (size_t)(kt*64 + kv) * DD + dk0;
      uint4 r0 = *(const uint4*)g;
      uint4 r1 = *(const uint4*)(g + DD);
      const u16* e0 = (const u16*)&r0;
      const u16* e1 = (const u16*)&r1;
      #pragma unroll
      for (int i = 0; i < 8; i++){
        int dk = dk0 + i;
        int sw = ((((dk >> 3) ^ dk) & 7) << 3);
        *(unsigned int*)&Vt[dk*64 + (kv ^ sw)] =
            (unsigned int)e0[i] | ((unsigned int)e1[i] << 16);
      }
    }
    __syncthreads();

    bf16x8 a0 = *(const bf16x8*)&Qs[(w*16+lr)*64 + ((lh*8) ^ qswz)];
    bf16x8 a1 = *(const bf16x8*)&Qs[(w*16+lr)*64 + ((32 + lh*8) ^ qswz)];
    f32x4 sc[4];
    #pragma unroll
    for (int j = 0; j < 4; j++){
      bf16x8 b0 = *(const bf16x8*)&Ks[(j*16+lr)*64 + ((lh*8) ^ qswz)];
      bf16x8 b1 = *(const bf16x8*)&Ks[(j*16+lr)*64 + ((32 + lh*8) ^ qswz)];
      f32x4 z = (f32x4){0.f,0.f,0.f,0.f};
      z = MFMA16(a0, b0, z);
      z = MFMA16(a1, b1, z);
      sc[j] = z;
    }

    float pr[4][4];
    float esc[4];
    #pragma unroll
    for (int r = 0; r < 4; r++){
      float mx = fmaxf(fmaxf(sc[0][r], sc[1][r]), fmaxf(sc[2][r], sc[3][r]));
      mx = fmaxf(mx, __shfl_xor(mx, 1));
      mx = fmaxf(mx, __shfl_xor(mx, 2));
      mx = fmaxf(mx, __shfl_xor(mx, 4));
      mx = fmaxf(mx, __shfl_xor(mx, 8));
      mx *= 0.125f;
      float m2 = fmaxf(mreg[r], mx);
      float scl = __expf(mreg[r] - m2);
      mreg[r] = m2;
      float s = 0.f;
      #pragma unroll
      for (int j = 0; j < 4; j++){
        float p = __expf(sc[j][r]*0.125f - m2);
        pr[j][r] = p;
        s += p;
      }
      s += __shfl_xor(s, 1);
      s += __shfl_xor(s, 2);
      s += __shfl_xor(s, 4);
      s += __shfl_xor(s, 8);
      lreg[r] = lreg[r]*scl + s;
      esc[r] = scl;
    }

    #pragma unroll
    for (int j = 0; j < 4; j++)
      #pragma unroll
      for (int r = 0; r < 4; r++){
        int prow = w*16 + lh*4 + r;
        int pcol = j*16 + lr;
        Ps[prow*64 + (pcol ^ (((lh*4 + r) & 7) << 3))] = f2b(pr[j][r]);
      }

    #pragma unroll
    for (int j = 0; j < 4; j++)
      #pragma unroll
      for (int r = 0; r < 4; r++) ofr[j][r] *= esc[r];

    bf16x8 pa0 = *(const bf16x8*)&Ps[(w*16+lr)*64 + ((lh*8) ^ qswz)];
    bf16x8 pa1 = *(const bf16x8*)&Ps[(w*16+lr)*64 + ((32 + lh*8) ^ qswz)];
    #pragma unroll
    for (int j = 0; j < 4; j++){
      int dkr = j*16 + lr;
      int sw = ((((dkr >> 3) ^ dkr) & 7) << 3);
      bf16x8 v0 = *(const bf16x8*)&Vt[dkr*64 + ((lh*8) ^ sw)];
      bf16x8 v1 = *(const bf16x8*)&Vt[dkr*64 + ((32 + lh*8) ^ sw)];
      ofr[j] = MFMA16(pa0, v0, ofr[j]);
      ofr[j] = MFMA16(pa1, v1, ofr[j]);
    }
    __syncthreads();
  }

  #pragma unroll
  for (int j = 0; j < 4; j++)
    #pragma unroll
    for (int r = 0; r < 4; r++){
      float v = ofr[j][r] / lreg[r];
      O[base + (size_t)(qt*64 + w*16 + lh*4 + r) * DD + j*16 + lr] = f2b(v);
    }
}

// ---------------- fused residual add + LayerNorm: wave per row, float4 loads ----------------
__global__ __launch_bounds__(256) void k_ln(const float* __restrict__ hin, const float* __restrict__ add,
    const float* __restrict__ g, const float* __restrict__ be,
    float* __restrict__ hout, u16* __restrict__ hb){
  const int w = threadIdx.x >> 6, lane = threadIdx.x & 63;
  const size_t row = (size_t)blockIdx.x * 4 + w;
  const size_t base = row * DD + lane * 8;
  float4 xa = *(const float4*)&hin[base];
  float4 xb = *(const float4*)&hin[base + 4];
  float4 aa = *(const float4*)&add[base];
  float4 ab = *(const float4*)&add[base + 4];
  float v[8] = { xa.x+aa.x, xa.y+aa.y, xa.z+aa.z, xa.w+aa.w,
                 xb.x+ab.x, xb.y+ab.y, xb.z+ab.z, xb.w+ab.w };
  float s = 0.f, q = 0.f;
  #pragma unroll
  for (int e = 0; e < 8; e++){ s += v[e]; q += v[e]*v[e]; }
  #pragma unroll
  for (int m = 32; m >= 1; m >>= 1){ s += __shfl_xor(s, m); q += __shfl_xor(q, m); }
  float mean = s * (1.f/512.f);
  float var  = q * (1.f/512.f) - mean*mean;
  float rstd = rsqrtf(var + 1e-5f);
  float4 g0 = *(const float4*)&g[lane*8],  g1 = *(const float4*)&g[lane*8+4];
  float4 b0 = *(const float4*)&be[lane*8], b1 = *(const float4*)&be[lane*8+4];
  float gv[8] = {g0.x,g0.y,g0.z,g0.w,g1.x,g1.y,g1.z,g1.w};
  float bv[8] = {b0.x,b0.y,b0.z,b0.w,b1.x,b1.y,b1.z,b1.w};
  float o[8];
  #pragma unroll
  for (int e = 0; e < 8; e++) o[e] = gv[e] * ((v[e]-mean)*rstd) + bv[e];
  *(float4*)&hout[base]     = make_float4(o[0],o[1],o[2],o[3]);
  *(float4*)&hout[base + 4] = make_float4(o[4],o[5],o[6],o[7]);
  uint4 pk;
  pk.x = (unsigned)f2b(o[0]) | ((unsigned)f2b(o[1])<<16);
  pk.y = (unsigned)f2b(o[2]) | ((unsigned)f2b(o[3])<<16);
  pk.z = (unsigned)f2b(o[4]) | ((unsigned)f2b(o[5])<<16);
  pk.w = (unsigned)f2b(o[6]) | ((unsigned)f2b(o[7])<<16);
  *(uint4*)&hb[base] = pk;
}

// ---------------- launch ----------------
extern "C" void kernel_launch(void* const* d_in, const int* in_sizes, int n_in,
                              void* d_out, int out_size, void* d_ws, size_t ws_size,
                              hipStream_t stream){
  const float* x   = (const float*)d_in[0];
  const float* WQ  = (const float*)d_in[1];
  const float* WK  = (const float*)d_in[2];
  const float* WV  = (const float*)d_in[3];
  const float* WO  = (const float*)d_in[4];
  const float* K1  = (const float*)d_in[5];
  const float* B1  = (const float*)d_in[6];
  const float* K2  = (const float*)d_in[7];
  const float* B2  = (const float*)d_in[8];
  const float* G1  = (const float*)d_in[9];
  const float* BE1 = (const float*)d_in[10];
  const float* G2  = (const float*)d_in[11];
  const float* BE2 = (const float*)d_in[12];
  float* hF = (float*)d_out;

  char* wp = (char*)d_ws;
  size_t off = 0;
  auto a16 = [&](size_t elems)->u16*{ u16* p = (u16*)(wp + off); off += elems*sizeof(u16); return p; };
  u16* WQt = a16((size_t)LB*DD*DD);
  u16* WKt = a16((size_t)LB*DD*DD);
  u16* WVt = a16((size_t)LB*DD*DD);
  u16* WOt = a16((size_t)LB*DD*DD);
  u16* K1t = a16((size_t)LB*DD*FF_);
  u16* K2t = a16((size_t)LB*DD*FF_);
  u16* hbf = a16((size_t)MM*DD);
  u16* qbf = a16((size_t)MM*DD);   // qbf,kbf,vbf contiguous (PERM epilogue relies on it)
  u16* kbf = a16((size_t)MM*DD);
  u16* vbf = a16((size_t)MM*DD);
  u16* abf = a16((size_t)MM*DD);
  u16* ff1 = qbf;  // alias: q/k/v/a dead when ff1 (MM x FF_) is live
  float* tmpF = (float*)(wp + off); off += (size_t)MM*DD*sizeof(float);
  (void)ws_size; (void)in_sizes; (void)n_in; (void)out_size;

  k_prep<<<MM*DD/4/256, 256, 0, stream>>>(x, hF, hbf);
  k_wt<<<dim3(8,8,LB),        256, 0, stream>>>(WQ, WQt, DD, DD);
  k_wt<<<dim3(8,8,LB),        256, 0, stream>>>(WK, WKt, DD, DD);
  k_wt<<<dim3(8,8,LB),        256, 0, stream>>>(WV, WVt, DD, DD);
  k_wt<<<dim3(8,8,LB),        256, 0, stream>>>(WO, WOt, DD, DD);
  k_wt<<<dim3(FF_/64,8,LB),   256, 0, stream>>>(K1, K1t, DD, FF_);
  k_wt<<<dim3(8,FF_/64,LB),   256, 0, stream>>>(K2, K2t, FF_, DD);

  for (int l = 0; l < LB; l++){
    const u16* wq = WQt + (size_t)l*DD*DD;
    const u16* wk = WKt + (size_t)l*DD*DD;
    const u16* wv = WVt + (size_t)l*DD*DD;
    const u16* wo = WOt + (size_t)l*DD*DD;
    const u16* k1 = K1t + (size_t)l*DD*FF_;
    const u16* k2 = K2t + (size_t)l*DD*FF_;

    // fused QKV: one 16384 x 1536 GEMM (head-fold PERM in B staging)
    k_gemm8<256,0,true ><<<dim3(64,6), 512, 0, stream>>>(hbf, wq, wk, wv, nullptr, nullptr, qbf, DD, DD);
    k_attn<<<dim3(SS/64, HH, BB), 256, 0, stream>>>(qbf, kbf, vbf, abf);
    k_gemm8<128,1,false><<<dim3(64,4), 512, 0, stream>>>(abf, wo, wo, wo, nullptr, tmpF, nullptr, DD, DD);
    k_ln<<<MM/4, 256, 0, stream>>>(hF, tmpF, G1 + l*DD, BE1 + l*DD, hF, hbf);
    k_gemm8<256,2,false><<<dim3(64,8), 512, 0, stream>>>(hbf, k1, k1, k1, B1 + (size_t)l*FF_, nullptr, ff1, FF_, DD);
    k_gemm8<128,3,false><<<dim3(64,4), 512, 0, stream>>>(ff1, k2, k2, k2, B2 + l*DD, tmpF, nullptr, DD, FF_);
    k_ln<<<MM/4, 256, 0, stream>>>(hF, tmpF, G2 + l*DD, BE2 + l*DD, hF, hbf);
  }
}

// Round 5
// 1828.383 us; speedup vs baseline: 1.1413x; 1.0138x over previous
//
#include <hip/hip_runtime.h>
#include <hip/hip_bf16.h>
#include <stdint.h>

#define LB 6
#define BB 32
#define SS 512
#define DD 512
#define HH 8
#define FF_ 2048
#define MM (BB*SS)   // 16384

typedef unsigned short u16;
typedef __attribute__((ext_vector_type(8))) short bf16x8;
typedef __attribute__((ext_vector_type(4))) float f32x4;

#define MFMA16(a,b,c) __builtin_amdgcn_mfma_f32_16x16x32_bf16((a),(b),(c),0,0,0)
#define GLD16(g, l) __builtin_amdgcn_global_load_lds( \
    (const __attribute__((address_space(1))) unsigned int*)(g), \
    (__attribute__((address_space(3))) unsigned int*)(l), 16, 0, 0)
#define BAR() asm volatile("s_barrier" ::: "memory")
#define VMW(n) asm volatile("s_waitcnt vmcnt(" #n ")" ::: "memory")

__device__ __forceinline__ u16 f2b(float f){
  unsigned int u = __float_as_uint(f);
  u = u + 0x7FFFu + ((u >> 16) & 1u);
  return (u16)(u >> 16);
}

// gelu via sigmoid identity: 0.5x(1+tanh(u)) == x * sigmoid(2u)
__device__ __forceinline__ float gelu_f(float x){
  float u2 = 1.5957691216057308f * (x + 0.044715f * x * x * x);
  return x / (1.0f + __expf(-u2));
}

// ---------------- prep: h(fp32)=x, hbf=bf16(x) ----------------
__global__ __launch_bounds__(256) void k_prep(const float* __restrict__ x,
                                              float* __restrict__ h,
                                              u16* __restrict__ hb){
  int i = blockIdx.x * 256 + threadIdx.x;
  float4 v = ((const float4*)x)[i];
  ((float4*)h)[i] = v;
  uint2 p;
  p.x = (unsigned)f2b(v.x) | ((unsigned)f2b(v.y) << 16);
  p.y = (unsigned)f2b(v.z) | ((unsigned)f2b(v.w) << 16);
  ((uint2*)hb)[i] = p;
}

// ---------------- weight transpose + bf16 cast: out[n][k] = in[k][n] ----------------
__global__ __launch_bounds__(256) void k_wt(const float* __restrict__ in,
                                            u16* __restrict__ out, int K, int N){
  size_t ms = (size_t)K * N;
  in  += ms * blockIdx.z;
  out += ms * blockIdx.z;
  int n0 = blockIdx.x * 64, k0 = blockIdx.y * 64;
  __shared__ float tile[64][65];
  int t = threadIdx.x;
  int c = t & 63, rb = t >> 6;
  #pragma unroll
  for (int p = 0; p < 16; p++){
    int k = p * 4 + rb;
    tile[k][c] = in[(size_t)(k0 + k) * N + (n0 + c)];
  }
  __syncthreads();
  #pragma unroll
  for (int p = 0; p < 16; p++){
    int n = p * 4 + rb;
    out[(size_t)(n0 + n) * K + (k0 + c)] = f2b(tile[c][n]);
  }
}

// ================ 8-phase 256-wide GEMM (T3+T4+T5, conflict-free frag-major LDS) ================
// out[m][n] = sum_k A[m][k]*Bt[n][k].  BM=256, BK=64, 8 waves (512 thr).
// BN=256: waves 2x4 (per-wave 128x64, acc[8][4]); BN=128: waves 4x2 (per-wave 64x64, acc[4][4]).
// EPI: 0 bf16, 1 fp32, 2 bias+gelu bf16, 3 bias fp32.  PERM: fused QKV head-fold.
template<int BN, int EPI, bool PERM>
__global__ __launch_bounds__(512, 1) void k_gemm8(
    const u16* __restrict__ A,
    const u16* __restrict__ Bq, const u16* __restrict__ Bk, const u16* __restrict__ Bv,
    const float* __restrict__ bias, float* __restrict__ outF, u16* __restrict__ outH,
    int N, int K)
{
  constexpr int WM = (BN==256) ? 2 : 4;
  constexpr int MR = 16/WM;
  constexpr int MQ = MR/4;
  constexpr int BHALF = (BN==256) ? 8192 : 4096;
  constexpr int BBUF  = 2*BHALF;
  constexpr int BL    = (BN==256) ? 2 : 1;
  constexpr int HC    = (BN==256) ? 128 : 64;
  __shared__ u16 sM[32768 + 2*BBUF];

  const int t = threadIdx.x;
  const int lane = t & 63, w = t >> 6, lr = lane & 15, lh = lane >> 4;
  const int wm = (BN==256) ? (w>>2) : (w>>1);
  const int wn = (BN==256) ? (w&3)  : (w&1);
  const int bm = blockIdx.x * 256, bn = blockIdx.y * BN;
  const int NTT = K >> 6, NIT = NTT >> 1;
  const int tz = PERM ? (bn >> 9) : 0;

  const int skA = (((t>>6)&1)<<5) + (((t>>4)&3)<<3);
  const int srA = ((t>>7)<<4) + (t&15);
  const u16* gA0 = A + (size_t)(bm +       srA) * K + skA;
  const u16* gA1 = A + (size_t)(bm + 128 + srA) * K + skA;
  const u16* gBp[2][2];
  {
    const u16* Bsel = PERM ? (tz==0 ? Bq : tz==1 ? Bk : Bv) : Bq;
    #pragma unroll
    for (int h = 0; h < 2; h++){
      #pragma unroll
      for (int s = 0; s < BL; s++){
        int n = (PERM ? (bn & 511) : bn) + h*HC + srA + s*64;
        int srow = PERM ? (((n & 63) << 3) | (n >> 6)) : n;
        gBp[h][s] = Bsel + (size_t)srow * K + skA;
      }
    }
  }

  auto stageA = [&](int kt, int h){
    u16* dst = sM + (kt&1)*16384 + h*8192 + t*8;
    const u16* src = (h ? gA1 : gA0) + kt*64;
    GLD16(src, dst);
    GLD16(src + (size_t)64*K, dst + 4096);
  };
  auto stageB = [&](int kt, int h){
    u16* dst = sM + 32768 + (kt&1)*BBUF + h*BHALF + t*8;
    GLD16(gBp[h][0] + kt*64, dst);
    if constexpr (BL == 2) GLD16(gBp[h][1] + kt*64, dst + 4096);
  };

  const int ha    = (BN==256) ? wm : (wm>>1);
  const int mbase = (BN==256) ? 0  : ((wm&1)*4);
  const int hbi   = (BN==256) ? (wn>>1) : wn;
  const int nfb   = (BN==256) ? ((wn&1)*4) : 0;
  const int rdAbase = ha*8192 + lane*8;
  const int rdBbase = 32768 + hbi*BHALF + nfb*1024 + lane*8;

  f32x4 acc[MR][4];
  #pragma unroll
  for (int i = 0; i < MR; i++)
    #pragma unroll
    for (int j = 0; j < 4; j++) acc[i][j] = (f32x4){0.f,0.f,0.f,0.f};
  bf16x8 bfr[4][2];

#define RD_A(d, q, af) { _Pragma("unroll") for (int i=0;i<MQ;i++){ _Pragma("unroll") for (int ks=0;ks<2;ks++) \
    af[i][ks] = *(const bf16x8*)&sM[(d)*16384 + rdAbase + ((mbase + (q)*MQ + i)*2 + ks)*512]; } }
#define RD_B(d) { _Pragma("unroll") for (int j=0;j<4;j++){ _Pragma("unroll") for (int ks=0;ks<2;ks++) \
    bfr[j][ks] = *(const bf16x8*)&sM[(d)*BBUF + rdBbase + ((j)*2 + (ks))*512]; } }
#define FMA_Q(q, af) { __builtin_amdgcn_s_setprio(1); \
  _Pragma("unroll") for (int i=0;i<MQ;i++){ _Pragma("unroll") for (int j=0;j<4;j++){ _Pragma("unroll") for (int ks=0;ks<2;ks++) \
    acc[(q)*MQ+i][j] = MFMA16(af[i][ks], bfr[j][ks], acc[(q)*MQ+i][j]); } } \
  __builtin_amdgcn_s_setprio(0); }

  stageA(0,0); stageA(0,1); stageB(0,0); stageB(0,1); stageB(1,0); stageB(1,1);
  if constexpr (BL == 2) { VMW(4); } else { VMW(2); }
  BAR();

  for (int it = 0; it < NIT; ++it){
    const int t0 = it*2;
    const bool lastit = (it == NIT-1);
    bf16x8 af[MQ][2];
    RD_A(0,0,af); RD_B(0); stageA(t0+1, 0);            BAR(); FMA_Q(0, af); BAR();
    RD_A(0,1,af);          stageA(t0+1, 1);            BAR(); FMA_Q(1, af); BAR();
    RD_A(0,2,af); if (t0+2 < NTT) stageB(t0+2, 0);     BAR(); FMA_Q(2, af); BAR();
    RD_A(0,3,af); if (t0+2 < NTT) stageB(t0+2, 1);     BAR(); FMA_Q(3, af);
    if (lastit) { VMW(0); } else { if constexpr (BL == 2) { VMW(4); } else { VMW(2); } }
    BAR();
    RD_A(1,0,af); RD_B(1); if (t0+2 < NTT) stageA(t0+2, 0); BAR(); FMA_Q(0, af); BAR();
    RD_A(1,1,af);          if (t0+2 < NTT) stageA(t0+2, 1); BAR(); FMA_Q(1, af); BAR();
    RD_A(1,2,af); if (t0+3 < NTT) stageB(t0+3, 0);     BAR(); FMA_Q(2, af); BAR();
    RD_A(1,3,af); if (t0+3 < NTT) stageB(t0+3, 1);     BAR(); FMA_Q(3, af);
    if (!lastit) { if constexpr (BL == 2) { VMW(4); } else { VMW(2); } }
    BAR();
  }
#undef RD_A
#undef RD_B
#undef FMA_Q

  #pragma unroll
  for (int mf = 0; mf < MR; mf++){
    const int row = bm + wm*(256/WM) + mf*16 + lh*4;
    #pragma unroll
    for (int j = 0; j < 4; j++){
      const int col = (PERM ? (bn & 511) : bn) + wn*64 + j*16 + lr;
      float bv = (EPI >= 2) ? bias[col] : 0.f;
      #pragma unroll
      for (int r = 0; r < 4; r++){
        float v = acc[mf][j][r];
        size_t o = (size_t)(row + r) * N + col;
        if (PERM) o += (size_t)tz * ((size_t)MM * DD);
        if (EPI == 0) outH[o] = f2b(v);
        else if (EPI == 1) outF[o] = v;
        else if (EPI == 2) outH[o] = f2b(gelu_f(v + bv));
        else outF[o] = v + bv;
      }
    }
  }
}

// ============== flash attention: QBLK=128, 8 waves, pipelined K-DMA / V-reg staging ==============
// Block = (qtile 128 rows, head, batch); 1D grid 1024 with XCD remap (h = L%8 so the 4 q-tiles
// of a (b,h) share an XCD L2).  Waves 0-3 stage V via regs (transpose+swizzle); waves 4-7 stage
// K via global_load_lds.  Next tile's loads are issued right after the barrier and consumed at
// the next barrier -> latency hidden under QK/softmax/PV.  One __syncthreads per kv-tile
// (its implicit vmcnt(0) drains exactly the loads we are about to read; nothing else in flight).
__global__ __launch_bounds__(512) void k_attn(const u16* __restrict__ Q, const u16* __restrict__ Kp,
                                              const u16* __restrict__ V, u16* __restrict__ O){
  const int L = blockIdx.x;
  const int hh = L & 7, qt = (L >> 3) & 3, b = L >> 5;
  __shared__ u16 Qs[8192];      // [128][64] row-xor-swizzled
  __shared__ u16 Ks[2][4096];   // [64][64]  row-xor-swizzled, double buffered
  __shared__ u16 Vt[2][4096];   // [dk][kv]  double-key swizzled, double buffered
  __shared__ u16 Ps[8192];      // [128][64] per-wave rows
  const int t = threadIdx.x, w = t >> 6, lane = t & 63, lr = lane & 15, lh = lane >> 4;
  const size_t base = ((size_t)b * SS) * DD + (size_t)hh * 64;

  // Q staging: all 8 waves, rows qt*128 + srow and +64
  {
    const int srow = t >> 3;
    const int gcol = (((t & 7) ^ (srow & 7)) << 3);
    const u16* g = Q + base + (size_t)(qt*128 + srow) * DD + gcol;
    GLD16(g,                 Qs + w*512);
    GLD16(g + (size_t)64*DD, Qs + 4096 + w*512);
  }
  // first K/V tile
  const int vdk0 = (t & 7) * 8, vkv = ((t >> 3) & 31) * 2;
  const int srow2 = ((w & 3) * 8) + (lane >> 3);
  const int gcol2 = (((lane & 7) ^ (srow2 & 7)) << 3);
  uint4 rv0, rv1;
  if (w < 4){
    const u16* g = V + base + (size_t)vkv * DD + vdk0;
    rv0 = *(const uint4*)g; rv1 = *(const uint4*)(g + DD);
  } else {
    const u16* g = Kp + base + (size_t)srow2 * DD + gcol2;
    GLD16(g,                 Ks[0] + (w-4)*512);
    GLD16(g + (size_t)32*DD, Ks[0] + 2048 + (w-4)*512);
  }

  float mreg[4], lreg[4];
  f32x4 ofr[4];
  #pragma unroll
  for (int r = 0; r < 4; r++){ mreg[r] = -1e30f; lreg[r] = 0.f; }
  #pragma unroll
  for (int j = 0; j < 4; j++) ofr[j] = (f32x4){0.f,0.f,0.f,0.f};

  const int qswz = (lr & 7) << 3;

  for (int kt = 0; kt < 8; kt++){
    const int bix = kt & 1;
    // write V(kt) regs -> Vt[bix] (waves 0-3); compiler waits the loads
    if (w < 4){
      const u16* e0 = (const u16*)&rv0;
      const u16* e1 = (const u16*)&rv1;
      #pragma unroll
      for (int i = 0; i < 8; i++){
        int dk = vdk0 + i;
        int sw = ((((dk >> 3) ^ dk) & 7) << 3);
        *(unsigned int*)&Vt[bix][dk*64 + (vkv ^ sw)] =
            (unsigned int)e0[i] | ((unsigned int)e1[i] << 16);
      }
    }
    __syncthreads();   // drains my K-DMA / V-writes; Ks[bix], Vt[bix] now valid for all

    // issue NEXT tile's loads -- in flight during the whole compute below
    if (kt < 7){
      if (w < 4){
        const u16* g = V + base + (size_t)((kt+1)*64 + vkv) * DD + vdk0;
        rv0 = *(const uint4*)g; rv1 = *(const uint4*)(g + DD);
      } else {
        const u16* g = Kp + base + (size_t)((kt+1)*64 + srow2) * DD + gcol2;
        GLD16(g,                 Ks[bix^1] + (w-4)*512);
        GLD16(g + (size_t)32*DD, Ks[bix^1] + 2048 + (w-4)*512);
      }
    }

    // QK^T: wave w owns Q rows w*16..w*16+15
    bf16x8 a0 = *(const bf16x8*)&Qs[(w*16+lr)*64 + ((lh*8) ^ qswz)];
    bf16x8 a1 = *(const bf16x8*)&Qs[(w*16+lr)*64 + ((32 + lh*8) ^ qswz)];
    f32x4 sc[4];
    #pragma unroll
    for (int j = 0; j < 4; j++){
      bf16x8 b0 = *(const bf16x8*)&Ks[bix][(j*16+lr)*64 + ((lh*8) ^ qswz)];
      bf16x8 b1 = *(const bf16x8*)&Ks[bix][(j*16+lr)*64 + ((32 + lh*8) ^ qswz)];
      f32x4 z = (f32x4){0.f,0.f,0.f,0.f};
      z = MFMA16(a0, b0, z);
      z = MFMA16(a1, b1, z);
      sc[j] = z;
    }

    // online softmax (rows = lh*4+r, reduce across 16 lanes)
    float pr[4][4];
    float esc[4];
    #pragma unroll
    for (int r = 0; r < 4; r++){
      float mx = fmaxf(fmaxf(sc[0][r], sc[1][r]), fmaxf(sc[2][r], sc[3][r]));
      mx = fmaxf(mx, __shfl_xor(mx, 1));
      mx = fmaxf(mx, __shfl_xor(mx, 2));
      mx = fmaxf(mx, __shfl_xor(mx, 4));
      mx = fmaxf(mx, __shfl_xor(mx, 8));
      mx *= 0.125f;
      float m2 = fmaxf(mreg[r], mx);
      float scl = __expf(mreg[r] - m2);
      mreg[r] = m2;
      float s = 0.f;
      #pragma unroll
      for (int j = 0; j < 4; j++){
        float p = __expf(sc[j][r]*0.125f - m2);
        pr[j][r] = p;
        s += p;
      }
      s += __shfl_xor(s, 1);
      s += __shfl_xor(s, 2);
      s += __shfl_xor(s, 4);
      s += __shfl_xor(s, 8);
      lreg[r] = lreg[r]*scl + s;
      esc[r] = scl;
    }

    // write P (bf16, swizzled); wave-private rows -> no barrier needed
    #pragma unroll
    for (int j = 0; j < 4; j++)
      #pragma unroll
      for (int r = 0; r < 4; r++){
        int prow = w*16 + lh*4 + r;
        int pcol = j*16 + lr;
        Ps[prow*64 + (pcol ^ (((lh*4 + r) & 7) << 3))] = f2b(pr[j][r]);
      }

    #pragma unroll
    for (int j = 0; j < 4; j++)
      #pragma unroll
      for (int r = 0; r < 4; r++) ofr[j][r] *= esc[r];

    // PV
    bf16x8 pa0 = *(const bf16x8*)&Ps[(w*16+lr)*64 + ((lh*8) ^ qswz)];
    bf16x8 pa1 = *(const bf16x8*)&Ps[(w*16+lr)*64 + ((32 + lh*8) ^ qswz)];
    #pragma unroll
    for (int j = 0; j < 4; j++){
      int dkr = j*16 + lr;
      int sw = ((((dkr >> 3) ^ dkr) & 7) << 3);
      bf16x8 v0 = *(const bf16x8*)&Vt[bix][dkr*64 + ((lh*8) ^ sw)];
      bf16x8 v1 = *(const bf16x8*)&Vt[bix][dkr*64 + ((32 + lh*8) ^ sw)];
      ofr[j] = MFMA16(pa0, v0, ofr[j]);
      ofr[j] = MFMA16(pa1, v1, ofr[j]);
    }
    // no trailing barrier: next iter writes only the OTHER buffers, and its own
    // __syncthreads blocks any wrap-around hazard (see header comment)
  }

  #pragma unroll
  for (int j = 0; j < 4; j++)
    #pragma unroll
    for (int r = 0; r < 4; r++){
      float v = ofr[j][r] / lreg[r];
      O[base + (size_t)(qt*128 + w*16 + lh*4 + r) * DD + j*16 + lr] = f2b(v);
    }
}

// ---------------- fused residual add + LayerNorm: wave per row, float4 loads ----------------
__global__ __launch_bounds__(256) void k_ln(const float* __restrict__ hin, const float* __restrict__ add,
    const float* __restrict__ g, const float* __restrict__ be,
    float* __restrict__ hout, u16* __restrict__ hb){
  const int w = threadIdx.x >> 6, lane = threadIdx.x & 63;
  const size_t row = (size_t)blockIdx.x * 4 + w;
  const size_t base = row * DD + lane * 8;
  float4 xa = *(const float4*)&hin[base];
  float4 xb = *(const float4*)&hin[base + 4];
  float4 aa = *(const float4*)&add[base];
  float4 ab = *(const float4*)&add[base + 4];
  float v[8] = { xa.x+aa.x, xa.y+aa.y, xa.z+aa.z, xa.w+aa.w,
                 xb.x+ab.x, xb.y+ab.y, xb.z+ab.z, xb.w+ab.w };
  float s = 0.f, q = 0.f;
  #pragma unroll
  for (int e = 0; e < 8; e++){ s += v[e]; q += v[e]*v[e]; }
  #pragma unroll
  for (int m = 32; m >= 1; m >>= 1){ s += __shfl_xor(s, m); q += __shfl_xor(q, m); }
  float mean = s * (1.f/512.f);
  float var  = q * (1.f/512.f) - mean*mean;
  float rstd = rsqrtf(var + 1e-5f);
  float4 g0 = *(const float4*)&g[lane*8],  g1 = *(const float4*)&g[lane*8+4];
  float4 b0 = *(const float4*)&be[lane*8], b1 = *(const float4*)&be[lane*8+4];
  float gv[8] = {g0.x,g0.y,g0.z,g0.w,g1.x,g1.y,g1.z,g1.w};
  float bv[8] = {b0.x,b0.y,b0.z,b0.w,b1.x,b1.y,b1.z,b1.w};
  float o[8];
  #pragma unroll
  for (int e = 0; e < 8; e++) o[e] = gv[e] * ((v[e]-mean)*rstd) + bv[e];
  *(float4*)&hout[base]     = make_float4(o[0],o[1],o[2],o[3]);
  *(float4*)&hout[base + 4] = make_float4(o[4],o[5],o[6],o[7]);
  uint4 pk;
  pk.x = (unsigned)f2b(o[0]) | ((unsigned)f2b(o[1])<<16);
  pk.y = (unsigned)f2b(o[2]) | ((unsigned)f2b(o[3])<<16);
  pk.z = (unsigned)f2b(o[4]) | ((unsigned)f2b(o[5])<<16);
  pk.w = (unsigned)f2b(o[6]) | ((unsigned)f2b(o[7])<<16);
  *(uint4*)&hb[base] = pk;
}

// ---------------- launch ----------------
extern "C" void kernel_launch(void* const* d_in, const int* in_sizes, int n_in,
                              void* d_out, int out_size, void* d_ws, size_t ws_size,
                              hipStream_t stream){
  const float* x   = (const float*)d_in[0];
  const float* WQ  = (const float*)d_in[1];
  const float* WK  = (const float*)d_in[2];
  const float* WV  = (const float*)d_in[3];
  const float* WO  = (const float*)d_in[4];
  const float* K1  = (const float*)d_in[5];
  const float* B1  = (const float*)d_in[6];
  const float* K2  = (const float*)d_in[7];
  const float* B2  = (const float*)d_in[8];
  const float* G1  = (const float*)d_in[9];
  const float* BE1 = (const float*)d_in[10];
  const float* G2  = (const float*)d_in[11];
  const float* BE2 = (const float*)d_in[12];
  float* hF = (float*)d_out;

  char* wp = (char*)d_ws;
  size_t off = 0;
  auto a16 = [&](size_t elems)->u16*{ u16* p = (u16*)(wp + off); off += elems*sizeof(u16); return p; };
  u16* WQt = a16((size_t)LB*DD*DD);
  u16* WKt = a16((size_t)LB*DD*DD);
  u16* WVt = a16((size_t)LB*DD*DD);
  u16* WOt = a16((size_t)LB*DD*DD);
  u16* K1t = a16((size_t)LB*DD*FF_);
  u16* K2t = a16((size_t)LB*DD*FF_);
  u16* hbf = a16((size_t)MM*DD);
  u16* qbf = a16((size_t)MM*DD);   // qbf,kbf,vbf contiguous (PERM epilogue relies on it)
  u16* kbf = a16((size_t)MM*DD);
  u16* vbf = a16((size_t)MM*DD);
  u16* abf = a16((size_t)MM*DD);
  u16* ff1 = qbf;  // alias: q/k/v/a dead when ff1 (MM x FF_) is live
  float* tmpF = (float*)(wp + off); off += (size_t)MM*DD*sizeof(float);
  (void)ws_size; (void)in_sizes; (void)n_in; (void)out_size;

  k_prep<<<MM*DD/4/256, 256, 0, stream>>>(x, hF, hbf);
  k_wt<<<dim3(8,8,LB),        256, 0, stream>>>(WQ, WQt, DD, DD);
  k_wt<<<dim3(8,8,LB),        256, 0, stream>>>(WK, WKt, DD, DD);
  k_wt<<<dim3(8,8,LB),        256, 0, stream>>>(WV, WVt, DD, DD);
  k_wt<<<dim3(8,8,LB),        256, 0, stream>>>(WO, WOt, DD, DD);
  k_wt<<<dim3(FF_/64,8,LB),   256, 0, stream>>>(K1, K1t, DD, FF_);
  k_wt<<<dim3(8,FF_/64,LB),   256, 0, stream>>>(K2, K2t, FF_, DD);

  for (int l = 0; l < LB; l++){
    const u16* wq = WQt + (size_t)l*DD*DD;
    const u16* wk = WKt + (size_t)l*DD*DD;
    const u16* wv = WVt + (size_t)l*DD*DD;
    const u16* wo = WOt + (size_t)l*DD*DD;
    const u16* k1 = K1t + (size_t)l*DD*FF_;
    const u16* k2 = K2t + (size_t)l*DD*FF_;

    // fused QKV: 16384 x 1536 GEMM, BN=128 -> 768 blocks = 3 exact CU rounds
    k_gemm8<128,0,true ><<<dim3(64,12), 512, 0, stream>>>(hbf, wq, wk, wv, nullptr, nullptr, qbf, DD, DD);
    k_attn<<<dim3(1024), 512, 0, stream>>>(qbf, kbf, vbf, abf);
    k_gemm8<128,1,false><<<dim3(64,4), 512, 0, stream>>>(abf, wo, wo, wo, nullptr, tmpF, nullptr, DD, DD);
    k_ln<<<MM/4, 256, 0, stream>>>(hF, tmpF, G1 + l*DD, BE1 + l*DD, hF, hbf);
    k_gemm8<256,2,false><<<dim3(64,8), 512, 0, stream>>>(hbf, k1, k1, k1, B1 + (size_t)l*FF_, nullptr, ff1, FF_, DD);
    k_gemm8<128,3,false><<<dim3(64,4), 512, 0, stream>>>(ff1, k2, k2, k2, B2 + l*DD, tmpF, nullptr, DD, FF_);
    k_ln<<<MM/4, 256, 0, stream>>>(hF, tmpF, G2 + l*DD, BE2 + l*DD, hF, hbf);
  }
}